// Round 4
// baseline (23.650 us; speedup 1.0000x reference)
//
#include <hip/hip_runtime.h>

#define B 4
#define NQ 512
#define NK 512
#define D 128
#define H 32
#define G 4                              // queries per attend block
#define PS 2.8853900817779268f           // 2*log2(e)

__device__ __forceinline__ float rcp_f(float x)  { return __builtin_amdgcn_rcpf(x); }
__device__ __forceinline__ float exp2_f(float x) { return __builtin_amdgcn_exp2f(x); }

__device__ __forceinline__ void fma4(float4& a, const float4& v, float s) {
    a.x = fmaf(s, v.x, a.x);
    a.y = fmaf(s, v.y, a.y);
    a.z = fmaf(s, v.z, a.z);
    a.w = fmaf(s, v.w, a.w);
}

// kh_t[b][h][k] = PS*(keys[b,k,:].Wk[:,h] + b1[h])   (transposed for attend)
// qh[b][q][h]   = PS*(queries[b,q,:].Wq[:,h])
__global__ __launch_bounds__(256) void proj_kernel(
    const float* __restrict__ keys, const float* __restrict__ queries,
    const float* __restrict__ Wk, const float* __restrict__ Wq,
    const float* __restrict__ b1,
    float* __restrict__ kh_t, float* __restrict__ qh)
{
    __shared__ float xs[8][D];
    const int tid = threadIdx.x;
    const int r0 = blockIdx.x * 8;
    const bool is_q = (r0 >= B * NK);
    const float* __restrict__ X = is_q ? (queries + (size_t)(r0 - B * NK) * D)
                                       : (keys + (size_t)r0 * D);
    const float* __restrict__ W = is_q ? Wq : Wk;

    reinterpret_cast<float4*>(&xs[0][0])[tid] =
        reinterpret_cast<const float4*>(X)[tid];
    __syncthreads();

    const int lr = tid >> 5;
    const int h  = tid & 31;
    float a0 = 0.f, a1 = 0.f, a2 = 0.f, a3 = 0.f;
    const float4* x4 = reinterpret_cast<const float4*>(&xs[lr][0]);
    #pragma unroll
    for (int i = 0; i < D / 4; ++i) {
        float4 v = x4[i];
        a0 = fmaf(v.x, W[(4 * i + 0) * H + h], a0);
        a1 = fmaf(v.y, W[(4 * i + 1) * H + h], a1);
        a2 = fmaf(v.z, W[(4 * i + 2) * H + h], a2);
        a3 = fmaf(v.w, W[(4 * i + 3) * H + h], a3);
    }
    float acc = (a0 + a1) + (a2 + a3);
    if (is_q) {
        const int rq = r0 - B * NK + lr;
        qh[(size_t)rq * H + h] = acc * PS;
    } else {
        const int r = r0 + lr;
        const int b = r >> 9;
        const int k = r & (NK - 1);
        kh_t[((size_t)b * H + h) * NK + k] = (acc + b1[h]) * PS;
    }
}

// One block per (b, group of G=4 queries). 256 threads = 4 waves.
// kh_t[b] (64KB) staged in LDS once per block; acc_s aliases the same LDS
// (phase-separated by barriers).
__global__ __launch_bounds__(256) void attend_kernel(
    const float* __restrict__ keys,
    const float* __restrict__ kh_t,   // [B][H][NK], pre-scaled, b1 folded in
    const float* __restrict__ qh,     // [B][NQ][H], pre-scaled
    const float* __restrict__ w2,
    float* __restrict__ outp)
{
    __shared__ float u_mem[H * NK];   // 64 KB: kh slab (ph1) / acc partials (ph2)
    __shared__ float ex_t[G][NK];     // 8 KB normalized softmax weights
    __shared__ float qv_s[G][H];
    __shared__ float w2_s[H];

    const int tid  = threadIdx.x;
    const int lane = tid & 63;
    const int w    = tid >> 6;
    const int b    = blockIdx.x >> 7;
    const int q0   = (blockIdx.x & 127) * G;

    // ---- stage kh_t[b] (64 KB) into LDS, coalesced float4 copy
    const float* khb = kh_t + (size_t)b * H * NK;
    {
        const float4* src = reinterpret_cast<const float4*>(khb);
        float4* dst = reinterpret_cast<float4*>(u_mem);
        #pragma unroll
        for (int i = 0; i < 16; ++i)
            dst[tid + 256 * i] = src[tid + 256 * i];
    }
    if (lane < H) {
        qv_s[w][lane] = qh[((size_t)b * NQ + q0 + w) * H + lane];
        if (w == 0) w2_s[lane] = -PS * w2[lane];
    }
    __syncthreads();

    // ---- phase 1: logits (log2-domain, const term dropped) for
    //      k = 4*lane + c (l[0..3]) and k = 256 + 4*lane + c (l[4..7])
    float l[8];
    #pragma unroll
    for (int j = 0; j < 8; ++j) l[j] = 0.f;
    #pragma unroll 8
    for (int h = 0; h < H; ++h) {
        const float4* row = reinterpret_cast<const float4*>(u_mem + h * NK);
        const float4 v0 = row[lane];          // 1 KB contiguous per wave
        const float4 v1 = row[lane + 64];
        const float qv = qv_s[w][h];          // LDS broadcast
        const float wp = w2_s[h];
        l[0] = fmaf(wp, rcp_f(1.f + exp2_f(qv + v0.x)), l[0]);
        l[1] = fmaf(wp, rcp_f(1.f + exp2_f(qv + v0.y)), l[1]);
        l[2] = fmaf(wp, rcp_f(1.f + exp2_f(qv + v0.z)), l[2]);
        l[3] = fmaf(wp, rcp_f(1.f + exp2_f(qv + v0.w)), l[3]);
        l[4] = fmaf(wp, rcp_f(1.f + exp2_f(qv + v1.x)), l[4]);
        l[5] = fmaf(wp, rcp_f(1.f + exp2_f(qv + v1.y)), l[5]);
        l[6] = fmaf(wp, rcp_f(1.f + exp2_f(qv + v1.z)), l[6]);
        l[7] = fmaf(wp, rcp_f(1.f + exp2_f(qv + v1.w)), l[7]);
    }

    // ---- wave-local softmax over 512 keys (8 per lane)
    float m = l[0];
    #pragma unroll
    for (int j = 1; j < 8; ++j) m = fmaxf(m, l[j]);
    #pragma unroll
    for (int off = 32; off; off >>= 1) m = fmaxf(m, __shfl_xor(m, off));
    float e[8], s = 0.f;
    #pragma unroll
    for (int j = 0; j < 8; ++j) { e[j] = exp2_f(l[j] - m); s += e[j]; }
    #pragma unroll
    for (int off = 32; off; off >>= 1) s += __shfl_xor(s, off);
    const float inv = 1.f / s;
    const float4 st0 = { e[0] * inv, e[1] * inv, e[2] * inv, e[3] * inv };
    const float4 st1 = { e[4] * inv, e[5] * inv, e[6] * inv, e[7] * inv };
    reinterpret_cast<float4*>(&ex_t[w][0])[lane]   = st0;
    reinterpret_cast<float4*>(&ex_t[w][256])[lane] = st1;
    __syncthreads();                      // also: all kh reads done -> acc may alias

    // ---- phase 2: context. thread (dg, kp): 64 keys, 4 d's, 4 queries;
    //      keys element read exactly once per block, coalesced.
    const int dg = tid & 31;
    const int kp = tid >> 5;
    const float4* k4 = reinterpret_cast<const float4*>(
        keys + ((size_t)b * NK + kp * 64) * D) + dg;
    const float4* e0p = reinterpret_cast<const float4*>(&ex_t[0][kp * 64]);
    const float4* e1p = reinterpret_cast<const float4*>(&ex_t[1][kp * 64]);
    const float4* e2p = reinterpret_cast<const float4*>(&ex_t[2][kp * 64]);
    const float4* e3p = reinterpret_cast<const float4*>(&ex_t[3][kp * 64]);
    float4 a0 = {0,0,0,0}, a1 = a0, a2 = a0, a3 = a0;
    #pragma unroll 4
    for (int kk4 = 0; kk4 < 16; ++kk4) {
        float ea[4], eb[4], ec[4], ed[4];
        *reinterpret_cast<float4*>(ea) = e0p[kk4];   // broadcast b128 reads
        *reinterpret_cast<float4*>(eb) = e1p[kk4];
        *reinterpret_cast<float4*>(ec) = e2p[kk4];
        *reinterpret_cast<float4*>(ed) = e3p[kk4];
        #pragma unroll
        for (int j = 0; j < 4; ++j) {
            float4 kv = k4[(size_t)(4 * kk4 + j) * (D / 4)];
            fma4(a0, kv, ea[j]);
            fma4(a1, kv, eb[j]);
            fma4(a2, kv, ec[j]);
            fma4(a3, kv, ed[j]);
        }
    }
    float (*acc_s)[G][D] = reinterpret_cast<float(*)[G][D]>(u_mem);  // aliases kh
    *reinterpret_cast<float4*>(&acc_s[kp][0][4 * dg]) = a0;
    *reinterpret_cast<float4*>(&acc_s[kp][1][4 * dg]) = a1;
    *reinterpret_cast<float4*>(&acc_s[kp][2][4 * dg]) = a2;
    *reinterpret_cast<float4*>(&acc_s[kp][3][4 * dg]) = a3;
    __syncthreads();

    // ---- reduce 8 partitions, write out. thread t -> float2 at flat offset 2t.
    const int o = 2 * tid;
    const int g = o >> 7;
    const int d = o & 127;
    float2 r = {0.f, 0.f};
    #pragma unroll
    for (int p = 0; p < 8; ++p) {
        float2 v = *reinterpret_cast<const float2*>(&acc_s[p][g][d]);
        r.x += v.x; r.y += v.y;
    }
    *reinterpret_cast<float2*>(&outp[((size_t)b * NQ + q0 + g) * D + d]) = r;
}

extern "C" void kernel_launch(void* const* d_in, const int* in_sizes, int n_in,
                              void* d_out, int out_size, void* d_ws, size_t ws_size,
                              hipStream_t stream) {
    const float* keys    = (const float*)d_in[0];
    const float* queries = (const float*)d_in[1];
    const float* Wk      = (const float*)d_in[2];
    const float* Wq      = (const float*)d_in[3];
    const float* b1      = (const float*)d_in[4];
    const float* w2      = (const float*)d_in[5];
    // d_in[6] = b2: dropped (softmax shift-invariant)
    float* out = (float*)d_out;

    float* kh_t = (float*)d_ws;                    // B*H*NK floats (transposed, pre-scaled)
    float* qh   = kh_t + (size_t)B * H * NK;       // B*NQ*H floats (pre-scaled)

    const int proj_blocks = (B * NK + B * NQ) / 8;   // 512
    proj_kernel<<<proj_blocks, 256, 0, stream>>>(keys, queries, Wk, Wq, b1, kh_t, qh);
    attend_kernel<<<B * NQ / G, 256, 0, stream>>>(keys, kh_t, qh, w2, out);
}